// Round 1
// baseline (255.324 us; speedup 1.0000x reference)
//
#include <hip/hip_runtime.h>
#include <hip/hip_bf16.h>

typedef __bf16 bf16_t;
typedef bf16_t bf16x8 __attribute__((ext_vector_type(8)));
typedef float  f32x4  __attribute__((ext_vector_type(4)));

#define MFMA16(A,B,C) __builtin_amdgcn_mfma_f32_16x16x32_bf16((A),(B),(C),0,0,0)

// NQ=16384, NK=4096, QDIM=512, KDIM=256, MID=256

// ---------------------------------------------------------------------------
// C_bf16[M][256] = (A_f32[M][KA] @ W_f32[256][KA]^T + b[256]) * scale
// Block: 64 M-rows x full N=256. 256 threads = 4 waves; wave w owns rows w*16.
// ---------------------------------------------------------------------------
template<int KA>
__global__ __launch_bounds__(256)
void proj_kernel(const float* __restrict__ A, const float* __restrict__ W,
                 const float* __restrict__ b, bf16_t* __restrict__ C,
                 float scale)
{
    __shared__ bf16_t Alds[64][40];    // 32 cols + pad to 40 (80B pitch -> 2-way max)
    __shared__ bf16_t Wlds[256][40];

    const int t  = threadIdx.x;
    const int w  = t >> 6, l = t & 63, lr = l & 15, lg = l >> 4;
    const int m0 = blockIdx.x * 64;

    f32x4 acc[16];
#pragma unroll
    for (int tt = 0; tt < 16; ++tt) acc[tt] = (f32x4){0.f, 0.f, 0.f, 0.f};

    const int ar  = t >> 2;            // A stage: row 0..63
    const int ac8 = (t & 3) * 8;       // col chunk

    for (int kb = 0; kb < KA / 32; ++kb) {
        // stage A tile [64][32] fp32 -> bf16
        {
            const float* ap = A + (size_t)(m0 + ar) * KA + kb * 32 + ac8;
            float4 a0 = *(const float4*)ap;
            float4 a1 = *(const float4*)(ap + 4);
            bf16x8 av;
            av[0]=(bf16_t)a0.x; av[1]=(bf16_t)a0.y; av[2]=(bf16_t)a0.z; av[3]=(bf16_t)a0.w;
            av[4]=(bf16_t)a1.x; av[5]=(bf16_t)a1.y; av[6]=(bf16_t)a1.z; av[7]=(bf16_t)a1.w;
            *(bf16x8*)&Alds[ar][ac8] = av;
        }
        // stage W tile [256][32] fp32 -> bf16 (4 chunks per thread)
#pragma unroll
        for (int c = 0; c < 4; ++c) {
            int e8 = c * 256 + t;
            int wr = e8 >> 2, wc8 = (e8 & 3) * 8;
            const float* wp = W + (size_t)wr * KA + kb * 32 + wc8;
            float4 w0 = *(const float4*)wp;
            float4 w1 = *(const float4*)(wp + 4);
            bf16x8 wv;
            wv[0]=(bf16_t)w0.x; wv[1]=(bf16_t)w0.y; wv[2]=(bf16_t)w0.z; wv[3]=(bf16_t)w0.w;
            wv[4]=(bf16_t)w1.x; wv[5]=(bf16_t)w1.y; wv[6]=(bf16_t)w1.z; wv[7]=(bf16_t)w1.w;
            *(bf16x8*)&Wlds[wr][wc8] = wv;
        }
        __syncthreads();

        bf16x8 af = *(bf16x8*)&Alds[w * 16 + lr][lg * 8];
#pragma unroll
        for (int tt = 0; tt < 16; ++tt) {
            bf16x8 bfrag = *(bf16x8*)&Wlds[tt * 16 + lr][lg * 8];
            acc[tt] = MFMA16(af, bfrag, acc[tt]);
        }
        __syncthreads();
    }

    // epilogue: bias, scale, cast, store
#pragma unroll
    for (int tt = 0; tt < 16; ++tt) {
        int col = tt * 16 + lr;
        float bias = b[col];
#pragma unroll
        for (int r = 0; r < 4; ++r) {
            int row = m0 + w * 16 + lg * 4 + r;
            C[(size_t)row * 256 + col] = (bf16_t)((acc[tt][r] + bias) * scale);
        }
    }
}

// ---------------------------------------------------------------------------
// VT[256][4096] bf16: VT[d][k] = w[k] * S[k][d]
// ---------------------------------------------------------------------------
__global__ __launch_bounds__(256)
void buildvt_kernel(const float* __restrict__ S, const float* __restrict__ wgt,
                    bf16_t* __restrict__ VT)
{
    int i = blockIdx.x * 256 + threadIdx.x;   // 0 .. 1048575
    int d = i >> 12, k = i & 4095;
    VT[i] = (bf16_t)(wgt[k] * S[(size_t)k * 256 + d]);
}

// ---------------------------------------------------------------------------
// Flash attention: out[16384][256] f32
// grid 256 blocks (64 q-rows each), 256 threads = 4 waves (16 q-rows/wave).
// ---------------------------------------------------------------------------
__global__ __launch_bounds__(256)
void attn_kernel(const bf16_t* __restrict__ Qb, const bf16_t* __restrict__ Kb,
                 const bf16_t* __restrict__ VT, const int* __restrict__ mask,
                 float* __restrict__ out)
{
    __shared__ bf16_t Klds[64][264];    // [kv][MID]  pitch 528B
    __shared__ bf16_t VTlds[256][72];   // [d][kv]    pitch 144B
    __shared__ bf16_t Plds[64][72];     // [q][kv]    pitch 144B

    const int t  = threadIdx.x;
    const int w  = t >> 6, l = t & 63, lr = l & 15, lg = l >> 4;
    const int q0 = blockIdx.x * 64;
    const int qw = q0 + w * 16;

    // hoist Q fragments (A-frag: row = lr, k = kk*32 + lg*8 + j)
    bf16x8 qf[8];
    {
        const bf16_t* qrow = Qb + (size_t)(qw + lr) * 256;
#pragma unroll
        for (int kk = 0; kk < 8; ++kk)
            qf[kk] = *(const bf16x8*)(qrow + kk * 32 + lg * 8);
    }

    f32x4 acc[16];
#pragma unroll
    for (int dt = 0; dt < 16; ++dt) acc[dt] = (f32x4){0.f, 0.f, 0.f, 0.f};
    float mrow[4], lsum[4];
#pragma unroll
    for (int r = 0; r < 4; ++r) { mrow[r] = -1e30f; lsum[r] = 0.f; }

    for (int kb = 0; kb < 64; ++kb) {
        // ---- stage K tile [64][256] (copy bf16)
#pragma unroll
        for (int c = 0; c < 8; ++c) {
            int e8 = c * 256 + t;
            int krow = e8 >> 5, kc8 = (e8 & 31) * 8;
            *(bf16x8*)&Klds[krow][kc8] =
                *(const bf16x8*)(Kb + (size_t)(kb * 64 + krow) * 256 + kc8);
        }
        // ---- stage VT tile [256][64]
#pragma unroll
        for (int c = 0; c < 8; ++c) {
            int e8 = c * 256 + t;
            int d = e8 >> 3, c8 = (e8 & 7) * 8;
            *(bf16x8*)&VTlds[d][c8] =
                *(const bf16x8*)(VT + (size_t)d * 4096 + kb * 64 + c8);
        }
        // ---- mask for this tile (C layout: row = lg*4+r, col = tt*16+lr)
        int mk[4][4];
#pragma unroll
        for (int tt = 0; tt < 4; ++tt)
#pragma unroll
            for (int r = 0; r < 4; ++r)
                mk[tt][r] = mask[(size_t)(qw + lg * 4 + r) * 4096 + kb * 64 + tt * 16 + lr];
        __syncthreads();

        // ---- S = Q K^T  (pre-scaled by 1/16 via Qb)
        f32x4 s[4];
#pragma unroll
        for (int tt = 0; tt < 4; ++tt) {
            f32x4 sv = (f32x4){0.f, 0.f, 0.f, 0.f};
#pragma unroll
            for (int kk = 0; kk < 8; ++kk) {
                bf16x8 kf = *(bf16x8*)&Klds[tt * 16 + lr][kk * 32 + lg * 8];
                sv = MFMA16(qf[kk], kf, sv);
            }
            s[tt] = sv;
        }
        // mask
#pragma unroll
        for (int tt = 0; tt < 4; ++tt)
#pragma unroll
            for (int r = 0; r < 4; ++r)
                s[tt][r] = mk[tt][r] ? s[tt][r] : -1e30f;

        // block row-max over 64 cols
        float bm[4];
#pragma unroll
        for (int r = 0; r < 4; ++r)
            bm[r] = fmaxf(fmaxf(s[0][r], s[1][r]), fmaxf(s[2][r], s[3][r]));
#pragma unroll
        for (int off = 1; off < 16; off <<= 1)
#pragma unroll
            for (int r = 0; r < 4; ++r)
                bm[r] = fmaxf(bm[r], __shfl_xor(bm[r], off));

        // online-softmax update
        float pr[4][4], rs[4];
#pragma unroll
        for (int r = 0; r < 4; ++r) {
            float mn = fmaxf(mrow[r], bm[r]);
            float fr = __expf(mrow[r] - mn);
            mrow[r] = mn;
            lsum[r] *= fr;
#pragma unroll
            for (int dt = 0; dt < 16; ++dt) acc[dt][r] *= fr;
            float sum = 0.f;
#pragma unroll
            for (int tt = 0; tt < 4; ++tt) {
                float p = __expf(s[tt][r] - mn);
                pr[tt][r] = p;
                sum += p;
            }
            rs[r] = sum;
        }
#pragma unroll
        for (int off = 1; off < 16; off <<= 1)
#pragma unroll
            for (int r = 0; r < 4; ++r)
                rs[r] += __shfl_xor(rs[r], off);
#pragma unroll
        for (int r = 0; r < 4; ++r) lsum[r] += rs[r];

        // ---- write P tile (bf16) to wave-private LDS rows
#pragma unroll
        for (int tt = 0; tt < 4; ++tt)
#pragma unroll
            for (int r = 0; r < 4; ++r)
                Plds[w * 16 + lg * 4 + r][tt * 16 + lr] = (bf16_t)pr[tt][r];
        asm volatile("s_waitcnt lgkmcnt(0)" ::: "memory");
        __builtin_amdgcn_sched_barrier(0);

        // ---- PV: acc[dt] += P[16x64] @ V[64x16]
        bf16x8 pa0 = *(bf16x8*)&Plds[w * 16 + lr][lg * 8];
        bf16x8 pa1 = *(bf16x8*)&Plds[w * 16 + lr][32 + lg * 8];
#pragma unroll
        for (int dt = 0; dt < 16; ++dt) {
            bf16x8 v0 = *(bf16x8*)&VTlds[dt * 16 + lr][lg * 8];
            bf16x8 v1 = *(bf16x8*)&VTlds[dt * 16 + lr][32 + lg * 8];
            acc[dt] = MFMA16(pa0, v0, acc[dt]);
            acc[dt] = MFMA16(pa1, v1, acc[dt]);
        }
        __syncthreads();
    }

    // epilogue: divide by softmax denominator, store f32
#pragma unroll
    for (int r = 0; r < 4; ++r) {
        float inv = 1.0f / lsum[r];
#pragma unroll
        for (int dt = 0; dt < 16; ++dt)
            out[(size_t)(qw + lg * 4 + r) * 256 + dt * 16 + lr] = acc[dt][r] * inv;
    }
}

// ---------------------------------------------------------------------------
extern "C" void kernel_launch(void* const* d_in, const int* in_sizes, int n_in,
                              void* d_out, int out_size, void* d_ws, size_t ws_size,
                              hipStream_t stream)
{
    const float* gE   = (const float*)d_in[0];  // [16384][512]
    const float* sE   = (const float*)d_in[1];  // [4096][256]
    const float* wgt  = (const float*)d_in[2];  // [4096]
    const int*   mask = (const int*)  d_in[3];  // [16384][4096]
    const float* Wq   = (const float*)d_in[4];  // [256][512]
    const float* bq   = (const float*)d_in[5];  // [256]
    const float* Wk   = (const float*)d_in[6];  // [256][256]
    const float* bk   = (const float*)d_in[7];  // [256]
    float* out = (float*)d_out;

    bf16_t* Qb = (bf16_t*)d_ws;                    // 16384*256 bf16 = 8 MB
    bf16_t* Kb = Qb + (size_t)16384 * 256;         // 4096*256  bf16 = 2 MB
    bf16_t* VT = Kb + (size_t)4096 * 256;          // 256*4096  bf16 = 2 MB

    if (ws_size < (size_t)(16384 * 256 + 4096 * 256 + 256 * 4096) * sizeof(bf16_t))
        return;  // workspace too small — fail loudly via validation

    // Q = (gE @ Wq^T + bq) / 16   (folds 1/sqrt(MID) into Q)
    proj_kernel<512><<<dim3(256, 1), 256, 0, stream>>>(gE, Wq, bq, Qb, 0.0625f);
    // K = sE @ Wk^T + bk
    proj_kernel<256><<<dim3(64, 1), 256, 0, stream>>>(sE, Wk, bk, Kb, 1.0f);
    // VT[d][k] = w[k] * sE[k][d]
    buildvt_kernel<<<4096, 256, 0, stream>>>(sE, wgt, VT);
    // fused masked softmax attention
    attn_kernel<<<256, 256, 0, stream>>>(Qb, Kb, VT, mask, out);
}